// Round 3
// baseline (271.046 us; speedup 1.0000x reference)
//
#include <hip/hip_runtime.h>

#define NX 8192
#define NKNOTS 132
#define NCOEFS 128
#define TILE_R 128   // rows per block
#define TILE_C 256   // cols per block

typedef float v4f __attribute__((ext_vector_type(4)));

// Cubic B-spline eval at v: span search matches the reference's degree-0
// indicator semantics (knots[i] <= v < knots[i+1]) on the actual knot values,
// then de Boor window recursion (identical arithmetic restricted to the 4
// nonzero bases; denominators strictly positive for spans 3..127 of this
// open-uniform vector). Verified absmax == 0.0 vs numpy in round 1.
__device__ __forceinline__ float eval_spline(float v,
                                             const float* __restrict__ kn,
                                             const float* __restrict__ c) {
    int span = 3 + (int)(v * 125.0f);
    span = min(127, max(3, span));
    while (span > 3 && v < kn[span]) span--;
    while (span < 127 && v >= kn[span + 1]) span++;

    float N[4], left[4], right[4];
    N[0] = 1.0f;
    #pragma unroll
    for (int j = 1; j <= 3; ++j) {
        left[j]  = v - kn[span + 1 - j];
        right[j] = kn[span + j] - v;
        float saved = 0.0f;
        #pragma unroll
        for (int r = 0; r < j; ++r) {
            float temp = N[r] / (right[r + 1] + left[j - r]);
            N[r] = saved + right[r + 1] * temp;
            saved = left[j - r] * temp;
        }
        N[j] = saved;
    }
    float s = 0.0f;
    #pragma unroll
    for (int r = 0; r <= 3; ++r) s += c[span - 3 + r] * N[r];
    return s;
}

// One fused kernel: each block owns a TILE_R x TILE_C output tile.
// Phase 1: eval the TILE_R sx values and TILE_C st values this tile needs
// (redundant across blocks, but ~0.8M cheap evals total).
// Phase 2: stream the outer-product tile with nontemporal float4 stores.
__global__ __launch_bounds__(256) void bspline_outer_fused(
        const float* __restrict__ x, const float* __restrict__ t,
        const float* __restrict__ knots, const float* __restrict__ coefs,
        const float* __restrict__ coefs_2, v4f* __restrict__ out) {
    __shared__ float kn[NKNOTS];
    __shared__ float cfx[NCOEFS];
    __shared__ float cft[NCOEFS];
    __shared__ float sx[TILE_R];
    __shared__ float st[TILE_C];

    const int tid = threadIdx.x;
    if (tid < NKNOTS) kn[tid] = knots[tid];
    if (tid < NCOEFS) {
        cfx[tid] = coefs[tid];
        cft[tid] = coefs_2[tid];
    }
    __syncthreads();

    const int row0 = blockIdx.y * TILE_R;
    const int col0 = blockIdx.x * TILE_C;

    // 256 threads: all eval one st column; first 128 also eval one sx row.
    st[tid] = eval_spline(t[col0 + tid], kn, cft);
    if (tid < TILE_R) sx[tid] = eval_spline(x[row0 + tid], kn, cfx);
    __syncthreads();

    // Phase 2: tile is TILE_R rows x 64 float4-cols. Each wave (lanes=tid&63)
    // covers row r0 = tid>>6 (+4 each iter), a full 64-float4 row segment ->
    // 1024 B contiguous per store instruction.
    const int col4 = tid & 63;           // float4 column within tile
    const int r0   = tid >> 6;           // 0..3
    const v4f stv = ((const v4f*)st)[col4];

    // float4 index of (row0+r0, col0) in the 8192x8192 output
    size_t idx = (size_t)(row0 + r0) * (NX / 4) + (size_t)(col0 / 4) + col4;

    #pragma unroll 8
    for (int k = 0; k < TILE_R / 4; ++k) {
        const float s = sx[r0 + 4 * k];   // wave-uniform LDS broadcast
        v4f o = s * stv;
        __builtin_nontemporal_store(o, &out[idx]);
        idx += (size_t)4 * (NX / 4);      // advance 4 rows
    }
}

extern "C" void kernel_launch(void* const* d_in, const int* in_sizes, int n_in,
                              void* d_out, int out_size, void* d_ws, size_t ws_size,
                              hipStream_t stream) {
    const float* x       = (const float*)d_in[0];
    const float* t       = (const float*)d_in[1];
    const float* knots   = (const float*)d_in[2];
    const float* coefs   = (const float*)d_in[3];
    const float* coefs_2 = (const float*)d_in[4];
    v4f* out = (v4f*)d_out;

    dim3 grid(NX / TILE_C, NX / TILE_R);   // 32 x 64 = 2048 blocks
    bspline_outer_fused<<<grid, 256, 0, stream>>>(x, t, knots, coefs, coefs_2,
                                                  out);
}

// Round 4
// 260.219 us; speedup vs baseline: 1.0416x; 1.0416x over previous
//
#include <hip/hip_runtime.h>

#define NX 8192
#define NKNOTS 132
#define NCOEFS 128
#define TILE_R 128   // rows per block
#define TILE_C 256   // cols per block

typedef float v4f __attribute__((ext_vector_type(4)));

// Cubic B-spline eval at v: span search matches the reference's degree-0
// indicator semantics (knots[i] <= v < knots[i+1]) on the actual knot values,
// then de Boor window recursion (identical arithmetic restricted to the 4
// nonzero bases; denominators strictly positive for spans 3..127 of this
// open-uniform vector). Verified absmax == 0.0 vs numpy in rounds 1 & 3.
__device__ __forceinline__ float eval_spline(float v,
                                             const float* __restrict__ kn,
                                             const float* __restrict__ c) {
    int span = 3 + (int)(v * 125.0f);
    span = min(127, max(3, span));
    while (span > 3 && v < kn[span]) span--;
    while (span < 127 && v >= kn[span + 1]) span++;

    float N[4], left[4], right[4];
    N[0] = 1.0f;
    #pragma unroll
    for (int j = 1; j <= 3; ++j) {
        left[j]  = v - kn[span + 1 - j];
        right[j] = kn[span + j] - v;
        float saved = 0.0f;
        #pragma unroll
        for (int r = 0; r < j; ++r) {
            float temp = N[r] / (right[r + 1] + left[j - r]);
            N[r] = saved + right[r + 1] * temp;
            saved = left[j - r] * temp;
        }
        N[j] = saved;
    }
    float s = 0.0f;
    #pragma unroll
    for (int r = 0; r <= 3; ++r) s += c[span - 3 + r] * N[r];
    return s;
}

// One fused kernel: each block owns a TILE_R x TILE_C output tile.
// Phase 1: eval the TILE_R sx values and TILE_C st values this tile needs
// (redundant across blocks, ~0.8M cheap evals total, overlapped with other
// blocks' store streams). Phase 2: stream the outer-product tile with
// regular float4 stores (the harness's own fill proves plain streaming
// writes hit the 6.5 TB/s ceiling; NT stores measured no better in R3).
__global__ __launch_bounds__(256) void bspline_outer_fused(
        const float* __restrict__ x, const float* __restrict__ t,
        const float* __restrict__ knots, const float* __restrict__ coefs,
        const float* __restrict__ coefs_2, v4f* __restrict__ out) {
    __shared__ float kn[NKNOTS];
    __shared__ float cfx[NCOEFS];
    __shared__ float cft[NCOEFS];
    __shared__ float sx[TILE_R];
    __shared__ float st[TILE_C];

    const int tid = threadIdx.x;
    if (tid < NKNOTS) kn[tid] = knots[tid];
    if (tid < NCOEFS) {
        cfx[tid] = coefs[tid];
        cft[tid] = coefs_2[tid];
    }
    __syncthreads();

    const int row0 = blockIdx.y * TILE_R;
    const int col0 = blockIdx.x * TILE_C;

    // 256 threads: all eval one st column; first 128 also eval one sx row.
    st[tid] = eval_spline(t[col0 + tid], kn, cft);
    if (tid < TILE_R) sx[tid] = eval_spline(x[row0 + tid], kn, cfx);
    __syncthreads();

    // Phase 2: tile is TILE_R rows x 64 float4-cols. Each wave (lanes=tid&63)
    // covers row r0 = tid>>6 (+4 each iter), a full 64-float4 row segment ->
    // 1024 B contiguous per store instruction.
    const int col4 = tid & 63;           // float4 column within tile
    const int r0   = tid >> 6;           // 0..3
    const v4f stv = ((const v4f*)st)[col4];

    // float4 index of (row0+r0, col0) in the 8192x8192 output
    size_t idx = (size_t)(row0 + r0) * (NX / 4) + (size_t)(col0 / 4) + col4;

    #pragma unroll 8
    for (int k = 0; k < TILE_R / 4; ++k) {
        const float s = sx[r0 + 4 * k];   // wave-uniform LDS broadcast
        out[idx] = s * stv;
        idx += (size_t)4 * (NX / 4);      // advance 4 rows
    }
}

extern "C" void kernel_launch(void* const* d_in, const int* in_sizes, int n_in,
                              void* d_out, int out_size, void* d_ws, size_t ws_size,
                              hipStream_t stream) {
    const float* x       = (const float*)d_in[0];
    const float* t       = (const float*)d_in[1];
    const float* knots   = (const float*)d_in[2];
    const float* coefs   = (const float*)d_in[3];
    const float* coefs_2 = (const float*)d_in[4];
    v4f* out = (v4f*)d_out;

    dim3 grid(NX / TILE_C, NX / TILE_R);   // 32 x 64 = 2048 blocks
    bspline_outer_fused<<<grid, 256, 0, stream>>>(x, t, knots, coefs, coefs_2,
                                                  out);
}